// Round 9
// baseline (261.001 us; speedup 1.0000x reference)
//
#include <hip/hip_runtime.h>
#include <hip/hip_bf16.h>

#define DEVFN __device__ __forceinline__
using bf16 = __hip_bfloat16;
typedef __attribute__((ext_vector_type(8))) short short8;
typedef __attribute__((ext_vector_type(4))) float f32x4;
typedef __attribute__((ext_vector_type(4))) unsigned short us4;

constexpr int BB = 4, NP = 256, NM = 128, CC = 128, HH = 128;
constexpr float EPS = 1e-5f;

#define MFMA16(a,b,c) __builtin_amdgcn_mfma_f32_16x16x32_bf16((a),(b),(c),0,0,0)

DEVFN unsigned short bfbits(float v){ union{ bf16 b; unsigned short s; } u; u.b = __float2bfloat16(v); return u.s; }
DEVFN float bits2f(unsigned short s){ union{ unsigned int i; float f; } u; u.i = ((unsigned)s) << 16; return u.f; }
DEVFN float sigm(float x){ return 1.0f / (1.0f + __expf(-x)); }

// ============================================================================
// prep: 6 weight matrices (128x128 f32, [k][n]) -> bf16 transposed Wt[n][k]
// order: 0:gw1 1:w1 2:gw2 3:w2 4:egw 5:asw
// ============================================================================
__global__ __launch_bounds__(256)
void prep_weights_kernel(const float* __restrict__ gw1, const float* __restrict__ w1,
                         const float* __restrict__ gw2, const float* __restrict__ w2,
                         const float* __restrict__ egw, const float* __restrict__ asw,
                         bf16* __restrict__ wt)
{
  __shared__ float wl[128][129];
  const int bx = blockIdx.x;
  const float* W = (bx==0)?gw1 : (bx==1)?w1 : (bx==2)?gw2 : (bx==3)?w2 : (bx==4)?egw : asw;
  const int t = threadIdx.x;
  for (int i = 0; i < 16; ++i){
    int idx = t + 256*i;
    int k = idx >> 5, n0 = (idx & 31) * 4;
    float4 v = *reinterpret_cast<const float4*>(W + k*128 + n0);
    wl[k][n0] = v.x; wl[k][n0+1] = v.y; wl[k][n0+2] = v.z; wl[k][n0+3] = v.w;
  }
  __syncthreads();
  short* o = reinterpret_cast<short*>(wt) + bx * 16384;
  const int n = t >> 1, kh = t & 1;
  #pragma unroll
  for (int j = 0; j < 8; ++j){
    short8 p;
    #pragma unroll
    for (int u = 0; u < 8; ++u) p[u] = (short)bfbits(wl[kh*64 + j*8 + u][n]);
    *reinterpret_cast<short8*>(o + n*128 + kh*64 + j*8) = p;
  }
}

// ============================================================================
// gate_all: ONE dispatch covering z (3 passes), pp (1 pass), mp (1 pass).
// 128-row tiles, 16x16x32 MFMA. Block types INTERLEAVED via bx%7 so each CU
// mixes compute-heavy z blocks with BW-heavy pp/mp blocks.
// Outputs channel-major: out[(b*128+h)*R + row]  (bf16)
// ============================================================================
struct GateSmem {
  short xs[128*128];     // swizzled bf16 A-tile: byte (r*256 + x) ^ ((r&7)<<4)
  float lgb[2][128];
  float mk[128];
};

DEVFN void gate_pass(const char* xb, const float* mk, int t, long obase, long R,
                     const short* wtg, const short* wtl,
                     const float* __restrict__ bgp, const float* __restrict__ blp,
                     bf16* outp)
{
  const int l = t & 63, w = t >> 6, lr = l & 15, lg = l >> 4;
  const int n0 = w * 32;
  short8 bgf[2][4], blf[2][4];
  #pragma unroll
  for (int nt = 0; nt < 2; ++nt)
    #pragma unroll
    for (int ks = 0; ks < 4; ++ks){
      int n = n0 + nt*16 + lr, ko = ks*32 + lg*8;
      bgf[nt][ks] = *reinterpret_cast<const short8*>(wtg + n*128 + ko);
      blf[nt][ks] = *reinterpret_cast<const short8*>(wtl + n*128 + ko);
    }
  float bgv[2] = { bgp[n0 + lr], bgp[n0 + 16 + lr] };
  float blv[2] = { blp[n0 + lr], blp[n0 + 16 + lr] };
  unsigned short* ob = reinterpret_cast<unsigned short*>(outp);

  for (int mt = 0; mt < 8; ++mt){
    f32x4 zv = {0.f,0.f,0.f,0.f};
    f32x4 ag0 = zv, ag1 = zv, al0 = zv, al1 = zv;
    #pragma unroll
    for (int ks = 0; ks < 4; ++ks){
      int m = mt*16 + lr, ko = ks*32 + lg*8;
      short8 a = *reinterpret_cast<const short8*>(xb + ((m*256 + ko*2) ^ ((m & 7) << 4)));
      ag0 = MFMA16(a, bgf[0][ks], ag0);
      al0 = MFMA16(a, blf[0][ks], al0);
      ag1 = MFMA16(a, bgf[1][ks], ag1);
      al1 = MFMA16(a, blf[1][ks], al1);
    }
    #pragma unroll
    for (int nt = 0; nt < 2; ++nt){
      f32x4 ag = nt ? ag1 : ag0, al = nt ? al1 : al0;
      int h = n0 + nt*16 + lr;
      us4 pk;
      #pragma unroll
      for (int rg = 0; rg < 4; ++rg){
        int rowl = mt*16 + lg*4 + rg;
        float val = sigm(ag[rg] + bgv[nt]) * (al[rg] + blv[nt]) * mk[rowl];
        pk[rg] = bfbits(val);
      }
      *reinterpret_cast<us4*>(ob + obase + (long)h*R + mt*16 + lg*4) = pk;
    }
  }
}

DEVFN void eg_pass(const char* xb, int t, long obase, long R,
                   const short* wtg, const float* __restrict__ bgp, bf16* outp)
{
  const int l = t & 63, w = t >> 6, lr = l & 15, lg = l >> 4;
  const int n0 = w * 32;
  short8 bgf[2][4];
  #pragma unroll
  for (int nt = 0; nt < 2; ++nt)
    #pragma unroll
    for (int ks = 0; ks < 4; ++ks){
      int n = n0 + nt*16 + lr, ko = ks*32 + lg*8;
      bgf[nt][ks] = *reinterpret_cast<const short8*>(wtg + n*128 + ko);
    }
  float bgv[2] = { bgp[n0 + lr], bgp[n0 + 16 + lr] };
  unsigned short* ob = reinterpret_cast<unsigned short*>(outp);

  for (int mt = 0; mt < 8; ++mt){
    f32x4 zv = {0.f,0.f,0.f,0.f};
    f32x4 ag0 = zv, ag1 = zv;
    #pragma unroll
    for (int ks = 0; ks < 4; ++ks){
      int m = mt*16 + lr, ko = ks*32 + lg*8;
      short8 a = *reinterpret_cast<const short8*>(xb + ((m*256 + ko*2) ^ ((m & 7) << 4)));
      ag0 = MFMA16(a, bgf[0][ks], ag0);
      ag1 = MFMA16(a, bgf[1][ks], ag1);
    }
    #pragma unroll
    for (int nt = 0; nt < 2; ++nt){
      f32x4 ag = nt ? ag1 : ag0;
      int h = n0 + nt*16 + lr;
      us4 pk;
      #pragma unroll
      for (int rg = 0; rg < 4; ++rg) pk[rg] = bfbits(sigm(ag[rg] + bgv[nt]));
      *reinterpret_cast<us4*>(ob + obase + (long)h*R + mt*16 + lg*4) = pk;
    }
  }
}

constexpr int NZB = (BB*NP*NM)/128;   // 1024
constexpr int NPB = (BB*NP*NP)/128;   // 2048
constexpr int NMB = (BB*NM*NM)/128;   // 512

__global__ __launch_bounds__(256, 4)
void gate_all_kernel(const float* __restrict__ z, const float* __restrict__ zmask,
                     const float* __restrict__ pp, const float* __restrict__ mp,
                     const float* __restrict__ lng, const float* __restrict__ lnb,
                     const bf16* __restrict__ wt,
                     const float* __restrict__ gb1, const float* __restrict__ b1,
                     const float* __restrict__ gb2, const float* __restrict__ b2,
                     const float* __restrict__ egbv,
                     bf16* ab1, bf16* ab2, bf16* egp, bf16* ppg, bf16* mpg)
{
  __shared__ GateSmem sm;
  const int t = threadIdx.x;
  const short* wts = reinterpret_cast<const short*>(wt);

  // interleave block types: 3584 = 512 groups of 7 -> {z,z,pp,pp,pp,pp,mp}
  const int g = blockIdx.x / 7, rm = blockIdx.x % 7;
  const float* x; const float* mask = nullptr;
  long R; int npass = 1; int bx;
  const short *w1g, *w1l; const float *bg1v, *bl1v; bf16* o1;
  if (rm < 2){
    bx = g*2 + rm;
    x = z; mask = zmask; R = (long)NP*NM; npass = 3;
    w1g = wts + 0*16384; w1l = wts + 1*16384; bg1v = gb1; bl1v = b1; o1 = ab1;
  } else if (rm < 6){
    bx = g*4 + (rm - 2);
    x = pp; R = (long)NP*NP;
    w1g = wts + 2*16384; w1l = wts + 3*16384; bg1v = gb2; bl1v = b2; o1 = ppg;
  } else {
    bx = g;
    x = mp; R = (long)NM*NM;
    w1g = wts + 0*16384; w1l = wts + 1*16384; bg1v = gb1; bl1v = b1; o1 = mpg;
  }
  const long row0 = (long)bx * 128;
  const int b = (int)(row0 / R);
  const long rowb = row0 - (long)b * R;
  const long obase = (long)b * 128 * R + rowb;

  if (t < 128){
    sm.lgb[0][t] = lng[t];
    sm.lgb[1][t] = lnb[t];
    sm.mk[t] = mask ? mask[row0 + t] : 1.0f;
  }

  // ---- LN fully in registers: 2 threads per row ----
  const int r = t >> 1, hf = t & 1;
  const float4* xrow = reinterpret_cast<const float4*>(x + (row0 + r)*128 + hf*64);
  float4 vb[16];
  float s = 0.f, ss = 0.f;
  #pragma unroll
  for (int i = 0; i < 16; ++i){
    float4 v = xrow[i]; vb[i] = v;
    s  += v.x + v.y + v.z + v.w;
    ss += v.x*v.x + v.y*v.y + v.z*v.z + v.w*v.w;
  }
  s  += __shfl_xor(s, 1);
  ss += __shfl_xor(ss, 1);
  const float mu = s * (1.f/128.f);
  const float rsg = rsqrtf(ss * (1.f/128.f) - mu*mu + EPS);
  __syncthreads();   // lgb/mk ready
  {
    char* xbw = reinterpret_cast<char*>(sm.xs);
    #pragma unroll
    for (int j = 0; j < 8; ++j){
      float4 a = vb[2*j], c2 = vb[2*j+1];
      float vv[8] = {a.x, a.y, a.z, a.w, c2.x, c2.y, c2.z, c2.w};
      short8 p;
      #pragma unroll
      for (int u = 0; u < 8; ++u){
        int ch = hf*64 + j*8 + u;
        p[u] = (short)bfbits((vv[u] - mu) * rsg * sm.lgb[0][ch] + sm.lgb[1][ch]);
      }
      *reinterpret_cast<short8*>(xbw + ((r*256 + hf*128 + j*16) ^ ((r & 7) << 4))) = p;
    }
  }
  __syncthreads();

  const char* xb = reinterpret_cast<const char*>(sm.xs);
  gate_pass(xb, sm.mk, t, obase, R, w1g, w1l, bg1v, bl1v, o1);
  if (npass == 3){
    gate_pass(xb, sm.mk, t, obase, R, wts + 2*16384, wts + 3*16384, gb2, b2, ab2);
    eg_pass(xb, t, obase, R, wts + 4*16384, egbv, egp);
  }
}

// ============================================================================
// einsum: per (b,c): bsum[b,c,i,j] = sum_k ppg[i,k]*ab1[k,j] + sum_k ab2[i,k]*mpg[j,k]
// ab1 staged to LDS transposed [j][k], dual-XOR swizzled. Output bf16.
// ============================================================================
DEVFN int b1swz(int j){ return (((j & 7) ^ ((j >> 3) & 7)) << 4); }

__global__ __launch_bounds__(256, 2)
void einsum_mfma_kernel(const bf16* __restrict__ ppg, const bf16* __restrict__ ab1,
                        const bf16* __restrict__ ab2, const bf16* __restrict__ mpg,
                        bf16* __restrict__ bsum)
{
  __shared__ short b1t[128*256];   // [j=128][k=256] bf16
  const int t = threadIdx.x, l = t & 63, w = t >> 6, lr = l & 15, lg = l >> 4;
  const int bc = blockIdx.x;
  const short* A1 = reinterpret_cast<const short*>(ppg) + (long)bc * (NP*NP);
  const short* B1 = reinterpret_cast<const short*>(ab1) + (long)bc * (NP*NM);
  const short* A2 = reinterpret_cast<const short*>(ab2) + (long)bc * (NP*NM);
  const short* B2 = reinterpret_cast<const short*>(mpg) + (long)bc * (NM*NM);

  char* lb = reinterpret_cast<char*>(b1t);
  for (int it = 0; it < 16; ++it){
    int idx = t + 256*it;               // 4096 chunks of 8 bf16
    int k = idx >> 4, j0 = (idx & 15) * 8;
    short8 v = *reinterpret_cast<const short8*>(B1 + idx*8);
    #pragma unroll
    for (int u = 0; u < 8; ++u){
      int j = j0 + u;
      *reinterpret_cast<short*>(lb + ((j*512 + k*2) ^ b1swz(j))) = v[u];
    }
  }
  __syncthreads();

  f32x4 zv = {0.f,0.f,0.f,0.f};
  f32x4 acc[4][8];
  #pragma unroll
  for (int i = 0; i < 4; ++i)
    #pragma unroll
    for (int j = 0; j < 8; ++j) acc[i][j] = zv;

  const int m0 = w * 64;
  // ---- e1: K = 256 ----
  for (int ks = 0; ks < 8; ++ks){
    int ko = ks*32 + lg*8;
    short8 af[4];
    #pragma unroll
    for (int mt = 0; mt < 4; ++mt)
      af[mt] = *reinterpret_cast<const short8*>(A1 + (m0 + mt*16 + lr)*256 + ko);
    short8 bf[8];
    #pragma unroll
    for (int nt = 0; nt < 8; ++nt){
      int n = nt*16 + lr;
      bf[nt] = *reinterpret_cast<const short8*>(lb + ((n*512 + ko*2) ^ b1swz(n)));
    }
    #pragma unroll
    for (int mt = 0; mt < 4; ++mt)
      #pragma unroll
      for (int nt = 0; nt < 8; ++nt)
        acc[mt][nt] = MFMA16(af[mt], bf[nt], acc[mt][nt]);
  }
  // ---- e2: K = 128 ----
  for (int ks = 0; ks < 4; ++ks){
    int ko = ks*32 + lg*8;
    short8 af[4];
    #pragma unroll
    for (int mt = 0; mt < 4; ++mt)
      af[mt] = *reinterpret_cast<const short8*>(A2 + (m0 + mt*16 + lr)*128 + ko);
    short8 bf[8];
    #pragma unroll
    for (int nt = 0; nt < 8; ++nt)
      bf[nt] = *reinterpret_cast<const short8*>(B2 + (nt*16 + lr)*128 + ko);
    #pragma unroll
    for (int mt = 0; mt < 4; ++mt)
      #pragma unroll
      for (int nt = 0; nt < 8; ++nt)
        acc[mt][nt] = MFMA16(af[mt], bf[nt], acc[mt][nt]);
  }
  // store bf16 [i][j]
  unsigned short* out = reinterpret_cast<unsigned short*>(bsum) + (long)bc * (NP*NM);
  #pragma unroll
  for (int mt = 0; mt < 4; ++mt)
    #pragma unroll
    for (int nt = 0; nt < 8; ++nt)
      #pragma unroll
      for (int rg = 0; rg < 4; ++rg)
        out[(m0 + mt*16 + lg*4 + rg)*128 + nt*16 + lr] = bfbits(acc[mt][nt][rg]);
}

// ============================================================================
// final: h = LN_c(bsum[b,c,ij]); out[ij,co] = eg[b,co,ij]*(h@asw + asb)*mask
// ============================================================================
__global__ __launch_bounds__(256, 2)
void final_mfma_kernel(const bf16* __restrict__ bsum, const bf16* __restrict__ eg,
                       const float* __restrict__ mask,
                       const float* __restrict__ lnhg, const float* __restrict__ lnhb,
                       const bf16* __restrict__ wt, const float* __restrict__ asb,
                       float* __restrict__ out)
{
  __shared__ struct {
    short xsT[128][72];    // [c][ij] bf16 (pad 72 -> 144B rows)
    short xs[64*128];      // swizzled bf16 A-tile [ij][c]
    float lgb[2][128];
    float ps[4][64], pss[4][64];
    float mu[64], rs[64], mk[64];
  } sm;
  const int t = threadIdx.x, l = t & 63, w = t >> 6, lr = l & 15, lg = l >> 4;
  const long row0 = (long)blockIdx.x * 64;
  const int b = (int)(row0 >> 15);          // 32768 rows per batch
  const long rowb = row0 & 32767;

  if (t < 128){ sm.lgb[0][t] = lnhg[t]; sm.lgb[1][t] = lnhb[t]; }
  if (t < 64) sm.mk[t] = mask[row0 + t];

  const short* bs = reinterpret_cast<const short*>(bsum);
  #pragma unroll
  for (int i = 0; i < 4; ++i){
    int idx = t + 256*i;              // 1024 chunks: c = idx>>3, j8 = idx&7
    int c = idx >> 3, j8 = idx & 7;
    short8 v = *reinterpret_cast<const short8*>(bs + (long)(b*128 + c)*32768 + rowb + j8*8);
    *reinterpret_cast<short8*>(&sm.xsT[c][j8*8]) = v;
  }
  __syncthreads();
  {
    int ij = t & 63, q = t >> 6;
    float s = 0.f, ss = 0.f;
    #pragma unroll
    for (int k = 0; k < 32; ++k){
      float v = bits2f((unsigned short)sm.xsT[q*32 + k][ij]);
      s += v; ss += v*v;
    }
    sm.ps[q][ij] = s; sm.pss[q][ij] = ss;
  }
  __syncthreads();
  if (t < 64){
    float s  = sm.ps[0][t] + sm.ps[1][t] + sm.ps[2][t] + sm.ps[3][t];
    float ss = sm.pss[0][t] + sm.pss[1][t] + sm.pss[2][t] + sm.pss[3][t];
    float mu = s * (1.f/128.f);
    float var = ss * (1.f/128.f) - mu*mu;
    sm.mu[t] = mu; sm.rs[t] = rsqrtf(var + EPS);
  }
  __syncthreads();
  {
    int ij = t & 63, q = t >> 6;
    float mu = sm.mu[ij], rg2 = sm.rs[ij];
    char* xbw = reinterpret_cast<char*>(sm.xs);
    #pragma unroll
    for (int u = 0; u < 4; ++u){
      short8 p;
      #pragma unroll
      for (int e = 0; e < 8; ++e){
        int c = q*32 + u*8 + e;
        float v = bits2f((unsigned short)sm.xsT[c][ij]);
        p[e] = (short)bfbits((v - mu) * rg2 * sm.lgb[0][c] + sm.lgb[1][c]);
      }
      *reinterpret_cast<short8*>(xbw + ((ij*256 + q*64 + u*16) ^ ((ij & 7) << 4))) = p;
    }
  }
  __syncthreads();

  // MFMA: wave w owns rows w*16..w*16+15, full N=128; B-frags loaded per ks
  const short* aswt = reinterpret_cast<const short*>(wt) + 5*16384;
  f32x4 zv = {0.f,0.f,0.f,0.f};
  f32x4 acc[8];
  #pragma unroll
  for (int i = 0; i < 8; ++i) acc[i] = zv;
  const char* xb = reinterpret_cast<const char*>(sm.xs);
  #pragma unroll
  for (int ks = 0; ks < 4; ++ks){
    int m = w*16 + lr, ko = ks*32 + lg*8;
    short8 a = *reinterpret_cast<const short8*>(xb + ((m*256 + ko*2) ^ ((m & 7) << 4)));
    #pragma unroll
    for (int nt = 0; nt < 8; ++nt){
      short8 bfr = *reinterpret_cast<const short8*>(aswt + (nt*16 + lr)*128 + ko);
      acc[nt] = MFMA16(a, bfr, acc[nt]);
    }
  }
  // epilogue
  const unsigned short* egb2 = reinterpret_cast<const unsigned short*>(eg);
  #pragma unroll
  for (int nt = 0; nt < 8; ++nt){
    int co = nt*16 + lr;
    float bias = asb[co];
    us4 egv = *reinterpret_cast<const us4*>(egb2 + (long)(b*128 + co)*32768 + rowb + w*16 + lg*4);
    #pragma unroll
    for (int rg = 0; rg < 4; ++rg){
      int rowl = w*16 + lg*4 + rg;
      float val = bits2f(egv[rg]) * (acc[nt][rg] + bias) * sm.mk[rowl];
      out[(row0 + rowl)*128 + co] = val;
    }
  }
}

// ============================================================================
extern "C" void kernel_launch(void* const* d_in, const int* in_sizes, int n_in,
                              void* d_out, int out_size, void* d_ws, size_t ws_size,
                              hipStream_t stream)
{
  const float* z     = (const float*)d_in[0];
  const float* zmask = (const float*)d_in[1];
  const float* pp    = (const float*)d_in[2];
  const float* mp    = (const float*)d_in[3];
  const float* ln_g  = (const float*)d_in[4];
  const float* ln_b  = (const float*)d_in[5];
  const float* lnh_g = (const float*)d_in[6];
  const float* lnh_b = (const float*)d_in[7];
  const float* gw1   = (const float*)d_in[8];
  const float* gb1   = (const float*)d_in[9];
  const float* gw2   = (const float*)d_in[10];
  const float* gb2   = (const float*)d_in[11];
  const float* w1    = (const float*)d_in[12];
  const float* b1    = (const float*)d_in[13];
  const float* w2    = (const float*)d_in[14];
  const float* b2    = (const float*)d_in[15];
  const float* egw   = (const float*)d_in[16];
  const float* egb   = (const float*)d_in[17];
  const float* asw   = (const float*)d_in[18];
  const float* asb   = (const float*)d_in[19];
  float* out = (float*)d_out;

  const size_t ZE = (size_t)BB*NP*NM*HH;   // 16,777,216
  const size_t PE = (size_t)BB*NP*NP*HH;   // 33,554,432
  const size_t ME = (size_t)BB*NM*NM*HH;   //  8,388,608
  char* ws = (char*)d_ws;
  size_t off = 0;
  bf16* wt   = (bf16*)(ws + off); off += 6 * 16384 * 2;
  bf16* ab1  = (bf16*)(ws + off); off += ZE * 2;
  bf16* ab2  = (bf16*)(ws + off); off += ZE * 2;
  bf16* egp  = (bf16*)(ws + off); off += ZE * 2;
  bf16* ppg  = (bf16*)(ws + off); off += PE * 2;
  bf16* mpg  = (bf16*)(ws + off); off += ME * 2;
  bf16* bsum = (bf16*)(ws + off); off += ZE * 2;
  if (ws_size < off) return;

  prep_weights_kernel<<<6, 256, 0, stream>>>(gw1, w1, gw2, w2, egw, asw, wt);

  gate_all_kernel<<<NZB + NPB + NMB, 256, 0, stream>>>(
      z, zmask, pp, mp, ln_g, ln_b, wt,
      gb1, b1, gb2, b2, egb,
      ab1, ab2, egp, ppg, mpg);

  einsum_mfma_kernel<<<BB*CC, 256, 0, stream>>>(ppg, ab1, ab2, mpg, bsum);

  final_mfma_kernel<<<(BB*NP*NM)/64, 256, 0, stream>>>(
      bsum, egp, zmask, lnh_g, lnh_b, wt, asb, out);
}

// Round 10
// 245.542 us; speedup vs baseline: 1.0630x; 1.0630x over previous
//
#include <hip/hip_runtime.h>
#include <hip/hip_bf16.h>

#define DEVFN __device__ __forceinline__
using bf16 = __hip_bfloat16;
typedef __attribute__((ext_vector_type(8))) short short8;
typedef __attribute__((ext_vector_type(4))) float f32x4;
typedef __attribute__((ext_vector_type(4))) unsigned short us4;

constexpr int BB = 4, NP = 256, NM = 128, CC = 128, HH = 128;
constexpr float EPS = 1e-5f;

#define MFMA16(a,b,c) __builtin_amdgcn_mfma_f32_16x16x32_bf16((a),(b),(c),0,0,0)

DEVFN unsigned short bfbits(float v){ union{ bf16 b; unsigned short s; } u; u.b = __float2bfloat16(v); return u.s; }
DEVFN float bits2f(unsigned short s){ union{ unsigned int i; float f; } u; u.i = ((unsigned)s) << 16; return u.f; }
DEVFN float sigm(float x){ return 1.0f / (1.0f + __expf(-x)); }

// Gate outputs use ROW-TILED channel-major layout:
//   elem(b, c, row) -> ((b*(R>>7) + (row>>7)) * 128 + c) * 128 + (row & 127)
// One 128-row gate block writes a contiguous 32KB region per tensor.

// ============================================================================
// prep: 6 weight matrices (128x128 f32, [k][n]) -> bf16 transposed Wt[n][k]
// order: 0:gw1 1:w1 2:gw2 3:w2 4:egw 5:asw
// ============================================================================
__global__ __launch_bounds__(256)
void prep_weights_kernel(const float* __restrict__ gw1, const float* __restrict__ w1,
                         const float* __restrict__ gw2, const float* __restrict__ w2,
                         const float* __restrict__ egw, const float* __restrict__ asw,
                         bf16* __restrict__ wt)
{
  __shared__ float wl[128][129];
  const int bx = blockIdx.x;
  const float* W = (bx==0)?gw1 : (bx==1)?w1 : (bx==2)?gw2 : (bx==3)?w2 : (bx==4)?egw : asw;
  const int t = threadIdx.x;
  for (int i = 0; i < 16; ++i){
    int idx = t + 256*i;
    int k = idx >> 5, n0 = (idx & 31) * 4;
    float4 v = *reinterpret_cast<const float4*>(W + k*128 + n0);
    wl[k][n0] = v.x; wl[k][n0+1] = v.y; wl[k][n0+2] = v.z; wl[k][n0+3] = v.w;
  }
  __syncthreads();
  short* o = reinterpret_cast<short*>(wt) + bx * 16384;
  const int n = t >> 1, kh = t & 1;
  #pragma unroll
  for (int j = 0; j < 8; ++j){
    short8 p;
    #pragma unroll
    for (int u = 0; u < 8; ++u) p[u] = (short)bfbits(wl[kh*64 + j*8 + u][n]);
    *reinterpret_cast<short8*>(o + n*128 + kh*64 + j*8) = p;
  }
}

// ============================================================================
// gate_all: ONE dispatch covering z (3 passes), pp (1 pass), mp (1 pass).
// 128-row tiles, 16x16x32 MFMA. Row-tiled channel-major output (dense 32KB
// writes per block per tensor).
// ============================================================================
struct GateSmem {
  short xs[128*128];     // swizzled bf16 A-tile: byte (r*256 + x) ^ ((r&7)<<4)
  float lgb[2][128];
  float mk[128];
};

DEVFN void gate_pass(const char* xb, const float* mk, int t, long obase,
                     const short* wtg, const short* wtl,
                     const float* __restrict__ bgp, const float* __restrict__ blp,
                     bf16* outp)
{
  const int l = t & 63, w = t >> 6, lr = l & 15, lg = l >> 4;
  const int n0 = w * 32;
  short8 bgf[2][4], blf[2][4];
  #pragma unroll
  for (int nt = 0; nt < 2; ++nt)
    #pragma unroll
    for (int ks = 0; ks < 4; ++ks){
      int n = n0 + nt*16 + lr, ko = ks*32 + lg*8;
      bgf[nt][ks] = *reinterpret_cast<const short8*>(wtg + n*128 + ko);
      blf[nt][ks] = *reinterpret_cast<const short8*>(wtl + n*128 + ko);
    }
  float bgv[2] = { bgp[n0 + lr], bgp[n0 + 16 + lr] };
  float blv[2] = { blp[n0 + lr], blp[n0 + 16 + lr] };
  unsigned short* ob = reinterpret_cast<unsigned short*>(outp);

  for (int mt = 0; mt < 8; ++mt){
    f32x4 zv = {0.f,0.f,0.f,0.f};
    f32x4 ag0 = zv, ag1 = zv, al0 = zv, al1 = zv;
    #pragma unroll
    for (int ks = 0; ks < 4; ++ks){
      int m = mt*16 + lr, ko = ks*32 + lg*8;
      short8 a = *reinterpret_cast<const short8*>(xb + ((m*256 + ko*2) ^ ((m & 7) << 4)));
      ag0 = MFMA16(a, bgf[0][ks], ag0);
      al0 = MFMA16(a, blf[0][ks], al0);
      ag1 = MFMA16(a, bgf[1][ks], ag1);
      al1 = MFMA16(a, blf[1][ks], al1);
    }
    #pragma unroll
    for (int nt = 0; nt < 2; ++nt){
      f32x4 ag = nt ? ag1 : ag0, al = nt ? al1 : al0;
      int h = n0 + nt*16 + lr;
      us4 pk;
      #pragma unroll
      for (int rg = 0; rg < 4; ++rg){
        int rowl = mt*16 + lg*4 + rg;
        float val = sigm(ag[rg] + bgv[nt]) * (al[rg] + blv[nt]) * mk[rowl];
        pk[rg] = bfbits(val);
      }
      *reinterpret_cast<us4*>(ob + obase + h*128 + mt*16 + lg*4) = pk;
    }
  }
}

DEVFN void eg_pass(const char* xb, int t, long obase,
                   const short* wtg, const float* __restrict__ bgp, bf16* outp)
{
  const int l = t & 63, w = t >> 6, lr = l & 15, lg = l >> 4;
  const int n0 = w * 32;
  short8 bgf[2][4];
  #pragma unroll
  for (int nt = 0; nt < 2; ++nt)
    #pragma unroll
    for (int ks = 0; ks < 4; ++ks){
      int n = n0 + nt*16 + lr, ko = ks*32 + lg*8;
      bgf[nt][ks] = *reinterpret_cast<const short8*>(wtg + n*128 + ko);
    }
  float bgv[2] = { bgp[n0 + lr], bgp[n0 + 16 + lr] };
  unsigned short* ob = reinterpret_cast<unsigned short*>(outp);

  for (int mt = 0; mt < 8; ++mt){
    f32x4 zv = {0.f,0.f,0.f,0.f};
    f32x4 ag0 = zv, ag1 = zv;
    #pragma unroll
    for (int ks = 0; ks < 4; ++ks){
      int m = mt*16 + lr, ko = ks*32 + lg*8;
      short8 a = *reinterpret_cast<const short8*>(xb + ((m*256 + ko*2) ^ ((m & 7) << 4)));
      ag0 = MFMA16(a, bgf[0][ks], ag0);
      ag1 = MFMA16(a, bgf[1][ks], ag1);
    }
    #pragma unroll
    for (int nt = 0; nt < 2; ++nt){
      f32x4 ag = nt ? ag1 : ag0;
      int h = n0 + nt*16 + lr;
      us4 pk;
      #pragma unroll
      for (int rg = 0; rg < 4; ++rg) pk[rg] = bfbits(sigm(ag[rg] + bgv[nt]));
      *reinterpret_cast<us4*>(ob + obase + h*128 + mt*16 + lg*4) = pk;
    }
  }
}

constexpr int NZB = (BB*NP*NM)/128;   // 1024
constexpr int NPB = (BB*NP*NP)/128;   // 2048
constexpr int NMB = (BB*NM*NM)/128;   // 512

__global__ __launch_bounds__(256, 3)
void gate_all_kernel(const float* __restrict__ z, const float* __restrict__ zmask,
                     const float* __restrict__ pp, const float* __restrict__ mp,
                     const float* __restrict__ lng, const float* __restrict__ lnb,
                     const bf16* __restrict__ wt,
                     const float* __restrict__ gb1, const float* __restrict__ b1,
                     const float* __restrict__ gb2, const float* __restrict__ b2,
                     const float* __restrict__ egbv,
                     bf16* ab1, bf16* ab2, bf16* egp, bf16* ppg, bf16* mpg)
{
  __shared__ GateSmem sm;
  const int t = threadIdx.x;
  const short* wts = reinterpret_cast<const short*>(wt);

  int bx = blockIdx.x;
  const float* x; const float* mask = nullptr;
  long R; int npass = 1;
  const short *w1g, *w1l; const float *bg1v, *bl1v; bf16* o1;
  if (bx < NZB){
    x = z; mask = zmask; R = (long)NP*NM; npass = 3;
    w1g = wts + 0*16384; w1l = wts + 1*16384; bg1v = gb1; bl1v = b1; o1 = ab1;
  } else if (bx < NZB + NPB){
    bx -= NZB; x = pp; R = (long)NP*NP;
    w1g = wts + 2*16384; w1l = wts + 3*16384; bg1v = gb2; bl1v = b2; o1 = ppg;
  } else {
    bx -= NZB + NPB; x = mp; R = (long)NM*NM;
    w1g = wts + 0*16384; w1l = wts + 1*16384; bg1v = gb1; bl1v = b1; o1 = mpg;
  }
  const long row0 = (long)bx * 128;
  const int b = (int)(row0 / R);
  const long rowb = row0 - (long)b * R;
  // row-tiled channel-major: contiguous 32KB block region
  const long obase = ((long)b * (R >> 7) + (rowb >> 7)) * 16384;

  if (t < 128){
    sm.lgb[0][t] = lng[t];
    sm.lgb[1][t] = lnb[t];
    sm.mk[t] = mask ? mask[row0 + t] : 1.0f;
  }

  // ---- LN fully in registers: 2 threads per row ----
  const int r = t >> 1, hf = t & 1;
  const float4* xrow = reinterpret_cast<const float4*>(x + (row0 + r)*128 + hf*64);
  float4 vb[16];
  float s = 0.f, ss = 0.f;
  #pragma unroll
  for (int i = 0; i < 16; ++i){
    float4 v = xrow[i]; vb[i] = v;
    s  += v.x + v.y + v.z + v.w;
    ss += v.x*v.x + v.y*v.y + v.z*v.z + v.w*v.w;
  }
  s  += __shfl_xor(s, 1);
  ss += __shfl_xor(ss, 1);
  const float mu = s * (1.f/128.f);
  const float rsg = rsqrtf(ss * (1.f/128.f) - mu*mu + EPS);
  __syncthreads();   // lgb/mk ready
  {
    char* xbw = reinterpret_cast<char*>(sm.xs);
    #pragma unroll
    for (int j = 0; j < 8; ++j){
      float4 a = vb[2*j], c2 = vb[2*j+1];
      float vv[8] = {a.x, a.y, a.z, a.w, c2.x, c2.y, c2.z, c2.w};
      short8 p;
      #pragma unroll
      for (int u = 0; u < 8; ++u){
        int ch = hf*64 + j*8 + u;
        p[u] = (short)bfbits((vv[u] - mu) * rsg * sm.lgb[0][ch] + sm.lgb[1][ch]);
      }
      *reinterpret_cast<short8*>(xbw + ((r*256 + hf*128 + j*16) ^ ((r & 7) << 4))) = p;
    }
  }
  __syncthreads();

  const char* xb = reinterpret_cast<const char*>(sm.xs);
  gate_pass(xb, sm.mk, t, obase, w1g, w1l, bg1v, bl1v, o1);
  if (npass == 3){
    gate_pass(xb, sm.mk, t, obase, wts + 2*16384, wts + 3*16384, gb2, b2, ab2);
    eg_pass(xb, t, obase, wts + 4*16384, egbv, egp);
  }
}

// ============================================================================
// einsum: per (b,c): bsum[b,c,i,j] = sum_k ppg[i,k]*ab1[k,j] + sum_k ab2[i,k]*mpg[j,k]
// Inputs in row-tiled channel-major layout. ab1 staged to LDS transposed
// [j][k], dual-XOR swizzled. Output bf16 (plain [b,c,i,j]).
// ============================================================================
DEVFN int b1swz(int j){ return (((j & 7) ^ ((j >> 3) & 7)) << 4); }

__global__ __launch_bounds__(256, 2)
void einsum_mfma_kernel(const bf16* __restrict__ ppg, const bf16* __restrict__ ab1,
                        const bf16* __restrict__ ab2, const bf16* __restrict__ mpg,
                        bf16* __restrict__ bsum)
{
  __shared__ short b1t[128*256];   // [j=128][k=256] bf16
  const int t = threadIdx.x, l = t & 63, w = t >> 6, lr = l & 15, lg = l >> 4;
  const int bc = blockIdx.x;
  const int b = bc >> 7, c = bc & 127;
  const short* A1s = reinterpret_cast<const short*>(ppg);
  const short* B1s = reinterpret_cast<const short*>(ab1);
  const short* A2s = reinterpret_cast<const short*>(ab2);
  const short* B2s = reinterpret_cast<const short*>(mpg);
  // per-(b,c) bases in row-tiled channel-major space
  const long a1base = ((long)b*512*128 + c) * 128;   // ppg: Rt=512
  const long b1base = ((long)b*256*128 + c) * 128;   // ab1: Rt=256, rt=k
  const long a2base = ((long)b*256*128 + c) * 128;   // ab2: Rt=256, rt=i
  const long b2base = ((long)b*128*128 + c) * 128;   // mpg: Rt=128, rt=j

  char* lb = reinterpret_cast<char*>(b1t);
  for (int it = 0; it < 16; ++it){
    int idx = t + 256*it;               // 4096 chunks of 8 bf16
    int k = idx >> 4, j0 = (idx & 15) * 8;
    short8 v = *reinterpret_cast<const short8*>(B1s + b1base + (long)k*16384 + j0);
    #pragma unroll
    for (int u = 0; u < 8; ++u){
      int j = j0 + u;
      *reinterpret_cast<short*>(lb + ((j*512 + k*2) ^ b1swz(j))) = v[u];
    }
  }
  __syncthreads();

  f32x4 zv = {0.f,0.f,0.f,0.f};
  f32x4 acc[4][8];
  #pragma unroll
  for (int i = 0; i < 4; ++i)
    #pragma unroll
    for (int j = 0; j < 8; ++j) acc[i][j] = zv;

  const int m0 = w * 64;
  // ---- e1: K = 256 ----
  for (int ks = 0; ks < 8; ++ks){
    int ko = ks*32 + lg*8;
    int koh = ko >> 7, kol = ko & 127;
    short8 af[4];
    #pragma unroll
    for (int mt = 0; mt < 4; ++mt){
      long m = m0 + mt*16 + lr;
      af[mt] = *reinterpret_cast<const short8*>(A1s + a1base + m*32768 + (long)koh*16384 + kol);
    }
    short8 bf[8];
    #pragma unroll
    for (int nt = 0; nt < 8; ++nt){
      int n = nt*16 + lr;
      bf[nt] = *reinterpret_cast<const short8*>(lb + ((n*512 + ko*2) ^ b1swz(n)));
    }
    #pragma unroll
    for (int mt = 0; mt < 4; ++mt)
      #pragma unroll
      for (int nt = 0; nt < 8; ++nt)
        acc[mt][nt] = MFMA16(af[mt], bf[nt], acc[mt][nt]);
  }
  // ---- e2: K = 128 ----
  for (int ks = 0; ks < 4; ++ks){
    int ko = ks*32 + lg*8;
    short8 af[4];
    #pragma unroll
    for (int mt = 0; mt < 4; ++mt){
      long m = m0 + mt*16 + lr;
      af[mt] = *reinterpret_cast<const short8*>(A2s + a2base + m*16384 + ko);
    }
    short8 bf[8];
    #pragma unroll
    for (int nt = 0; nt < 8; ++nt){
      long n = nt*16 + lr;
      bf[nt] = *reinterpret_cast<const short8*>(B2s + b2base + n*16384 + ko);
    }
    #pragma unroll
    for (int mt = 0; mt < 4; ++mt)
      #pragma unroll
      for (int nt = 0; nt < 8; ++nt)
        acc[mt][nt] = MFMA16(af[mt], bf[nt], acc[mt][nt]);
  }
  // store bf16 [i][j]  (plain per-(b,c) contiguous layout)
  unsigned short* out = reinterpret_cast<unsigned short*>(bsum) + (long)bc * (NP*NM);
  #pragma unroll
  for (int mt = 0; mt < 4; ++mt)
    #pragma unroll
    for (int nt = 0; nt < 8; ++nt)
      #pragma unroll
      for (int rg = 0; rg < 4; ++rg)
        out[(m0 + mt*16 + lg*4 + rg)*128 + nt*16 + lr] = bfbits(acc[mt][nt][rg]);
}

// ============================================================================
// final: h = LN_c(bsum[b,c,ij]); out[ij,co] = eg[b,co,ij]*(h@asw + asb)*mask
// eg in row-tiled channel-major layout.
// ============================================================================
__global__ __launch_bounds__(256, 2)
void final_mfma_kernel(const bf16* __restrict__ bsum, const bf16* __restrict__ eg,
                       const float* __restrict__ mask,
                       const float* __restrict__ lnhg, const float* __restrict__ lnhb,
                       const bf16* __restrict__ wt, const float* __restrict__ asb,
                       float* __restrict__ out)
{
  __shared__ struct {
    short xsT[128][72];    // [c][ij] bf16 (pad 72 -> 144B rows)
    short xs[64*128];      // swizzled bf16 A-tile [ij][c]
    float lgb[2][128];
    float ps[4][64], pss[4][64];
    float mu[64], rs[64], mk[64];
  } sm;
  const int t = threadIdx.x, l = t & 63, w = t >> 6, lr = l & 15, lg = l >> 4;
  const long row0 = (long)blockIdx.x * 64;
  const int b = (int)(row0 >> 15);          // 32768 rows per batch
  const long rowb = row0 & 32767;

  if (t < 128){ sm.lgb[0][t] = lnhg[t]; sm.lgb[1][t] = lnhb[t]; }
  if (t < 64) sm.mk[t] = mask[row0 + t];

  const short* bs = reinterpret_cast<const short*>(bsum);
  #pragma unroll
  for (int i = 0; i < 4; ++i){
    int idx = t + 256*i;              // 1024 chunks: c = idx>>3, j8 = idx&7
    int c = idx >> 3, j8 = idx & 7;
    short8 v = *reinterpret_cast<const short8*>(bs + (long)(b*128 + c)*32768 + rowb + j8*8);
    *reinterpret_cast<short8*>(&sm.xsT[c][j8*8]) = v;
  }
  __syncthreads();
  {
    int ij = t & 63, q = t >> 6;
    float s = 0.f, ss = 0.f;
    #pragma unroll
    for (int k = 0; k < 32; ++k){
      float v = bits2f((unsigned short)sm.xsT[q*32 + k][ij]);
      s += v; ss += v*v;
    }
    sm.ps[q][ij] = s; sm.pss[q][ij] = ss;
  }
  __syncthreads();
  if (t < 64){
    float s  = sm.ps[0][t] + sm.ps[1][t] + sm.ps[2][t] + sm.ps[3][t];
    float ss = sm.pss[0][t] + sm.pss[1][t] + sm.pss[2][t] + sm.pss[3][t];
    float mu = s * (1.f/128.f);
    float var = ss * (1.f/128.f) - mu*mu;
    sm.mu[t] = mu; sm.rs[t] = rsqrtf(var + EPS);
  }
  __syncthreads();
  {
    int ij = t & 63, q = t >> 6;
    float mu = sm.mu[ij], rg2 = sm.rs[ij];
    char* xbw = reinterpret_cast<char*>(sm.xs);
    #pragma unroll
    for (int u = 0; u < 4; ++u){
      short8 p;
      #pragma unroll
      for (int e = 0; e < 8; ++e){
        int c = q*32 + u*8 + e;
        float v = bits2f((unsigned short)sm.xsT[c][ij]);
        p[e] = (short)bfbits((v - mu) * rg2 * sm.lgb[0][c] + sm.lgb[1][c]);
      }
      *reinterpret_cast<short8*>(xbw + ((ij*256 + q*64 + u*16) ^ ((ij & 7) << 4))) = p;
    }
  }
  __syncthreads();

  // MFMA: wave w owns rows w*16..w*16+15, full N=128; B-frags loaded per ks
  const short* aswt = reinterpret_cast<const short*>(wt) + 5*16384;
  f32x4 zv = {0.f,0.f,0.f,0.f};
  f32x4 acc[8];
  #pragma unroll
  for (int i = 0; i < 8; ++i) acc[i] = zv;
  const char* xb = reinterpret_cast<const char*>(sm.xs);
  #pragma unroll
  for (int ks = 0; ks < 4; ++ks){
    int m = w*16 + lr, ko = ks*32 + lg*8;
    short8 a = *reinterpret_cast<const short8*>(xb + ((m*256 + ko*2) ^ ((m & 7) << 4)));
    #pragma unroll
    for (int nt = 0; nt < 8; ++nt){
      short8 bfr = *reinterpret_cast<const short8*>(aswt + (nt*16 + lr)*128 + ko);
      acc[nt] = MFMA16(a, bfr, acc[nt]);
    }
  }
  // epilogue — eg read from row-tiled channel-major layout
  const unsigned short* egb2 = reinterpret_cast<const unsigned short*>(eg);
  const long egbase = ((long)b*256 + (rowb >> 7)) * 16384;
  const int rsub = (int)(rowb & 64);
  #pragma unroll
  for (int nt = 0; nt < 8; ++nt){
    int co = nt*16 + lr;
    float bias = asb[co];
    us4 egv = *reinterpret_cast<const us4*>(egb2 + egbase + co*128 + rsub + w*16 + lg*4);
    #pragma unroll
    for (int rg = 0; rg < 4; ++rg){
      int rowl = w*16 + lg*4 + rg;
      float val = bits2f(egv[rg]) * (acc[nt][rg] + bias) * sm.mk[rowl];
      out[(row0 + rowl)*128 + co] = val;
    }
  }
}

// ============================================================================
extern "C" void kernel_launch(void* const* d_in, const int* in_sizes, int n_in,
                              void* d_out, int out_size, void* d_ws, size_t ws_size,
                              hipStream_t stream)
{
  const float* z     = (const float*)d_in[0];
  const float* zmask = (const float*)d_in[1];
  const float* pp    = (const float*)d_in[2];
  const float* mp    = (const float*)d_in[3];
  const float* ln_g  = (const float*)d_in[4];
  const float* ln_b  = (const float*)d_in[5];
  const float* lnh_g = (const float*)d_in[6];
  const float* lnh_b = (const float*)d_in[7];
  const float* gw1   = (const float*)d_in[8];
  const float* gb1   = (const float*)d_in[9];
  const float* gw2   = (const float*)d_in[10];
  const float* gb2   = (const float*)d_in[11];
  const float* w1    = (const float*)d_in[12];
  const float* b1    = (const float*)d_in[13];
  const float* w2    = (const float*)d_in[14];
  const float* b2    = (const float*)d_in[15];
  const float* egw   = (const float*)d_in[16];
  const float* egb   = (const float*)d_in[17];
  const float* asw   = (const float*)d_in[18];
  const float* asb   = (const float*)d_in[19];
  float* out = (float*)d_out;

  const size_t ZE = (size_t)BB*NP*NM*HH;   // 16,777,216
  const size_t PE = (size_t)BB*NP*NP*HH;   // 33,554,432
  const size_t ME = (size_t)BB*NM*NM*HH;   //  8,388,608
  char* ws = (char*)d_ws;
  size_t off = 0;
  bf16* wt   = (bf16*)(ws + off); off += 6 * 16384 * 2;
  bf16* ab1  = (bf16*)(ws + off); off += ZE * 2;
  bf16* ab2  = (bf16*)(ws + off); off += ZE * 2;
  bf16* egp  = (bf16*)(ws + off); off += ZE * 2;
  bf16* ppg  = (bf16*)(ws + off); off += PE * 2;
  bf16* mpg  = (bf16*)(ws + off); off += ME * 2;
  bf16* bsum = (bf16*)(ws + off); off += ZE * 2;
  if (ws_size < off) return;

  prep_weights_kernel<<<6, 256, 0, stream>>>(gw1, w1, gw2, w2, egw, asw, wt);

  gate_all_kernel<<<NZB + NPB + NMB, 256, 0, stream>>>(
      z, zmask, pp, mp, ln_g, ln_b, wt,
      gb1, b1, gb2, b2, egb,
      ab1, ab2, egp, ppg, mpg);

  einsum_mfma_kernel<<<BB*CC, 256, 0, stream>>>(ppg, ab1, ab2, mpg, bsum);

  final_mfma_kernel<<<(BB*NP*NM)/64, 256, 0, stream>>>(
      bsum, egp, zmask, lnh_g, lnh_b, wt, asb, out);
}